// Round 1
// baseline (268.880 us; speedup 1.0000x reference)
//
#include <hip/hip_runtime.h>

#define HWSZ 65536      // H*W
#define KSEL 32768u     // int(0.5*H*W)
#define CCH  128        // channels
#define BN   4          // batch
#define NG   (CCH * BN) // 512 groups; group g = b*CCH + c, contiguous HWSZ floats
#define NT   256        // threads per block (4 waves)
#define EPT  (HWSZ / NT)        // 256 elements per thread

#define NB1  128                // level-1 bins (coarse)
#define NB2  64                 // level-2 sub-bins inside boundary bin
#define H1S  (NB1 + 1)          // padded stride (u16 units) — spreads hot bin over banks
#define H2S  (NB2 + 1)          // padded stride (u32 words)
#define SMW  16640              // union size in u32 words: max(256*129/2=16512, 256*65=16640)

#define FIXSCALE 1073741824.0f  // 2^30 fixed point for exact sums
#define Q15SCALE 32768.0f       // 2^15 fixed point for boundary-bin sums

// Two streaming passes, zero LDS atomics.
// Pass 1: private u16 count hist (128 bins) + exact total. Pass 2 (L3-resident
// re-read): exact sum of bins > cb + private packed (cnt<<22|q15) 64-sub-bin hist
// inside cb. Effective 8192-bin grid == previous verified kernel's resolution.
__global__ void __launch_bounds__(NT) passA_kernel(
    const float* __restrict__ hsi, const float* __restrict__ wp,
    double* __restrict__ total_sum, double* __restrict__ topk_sum) {
    __shared__ unsigned smem[SMW];                 // 65 KB union: hist1(u16) / hist2(u32)
    __shared__ unsigned long long totArr[NT];      // 2 KB
    __shared__ unsigned long long highArr[NT];     // 2 KB
    __shared__ unsigned cnt1[NB1];                 // 512 B
    __shared__ unsigned part1[2][NB1];             // 1 KB
    __shared__ unsigned cnt2[NB2];                 // 256 B
    __shared__ unsigned sum2[NB2];                 // 256 B
    __shared__ unsigned pc2[4][NB2];               // 1 KB
    __shared__ unsigned ps2[4][NB2];               // 1 KB
    __shared__ int s_cb;
    __shared__ unsigned s_accAbove;

    const int g   = blockIdx.x;
    const int tid = threadIdx.x;
    const float w = wp[0];

    // upper bound on e = -f1*ln(f1), f1 in (0, w): 1/e if w>=1/e else -w ln w
    float emax = (w < 0.367879441f) ? (-w * __logf(w)) : 0.3678794412f;
    emax *= 1.000004f;                             // fp slack so no value exceeds range
    const float scale1 = (float)NB1 / emax;
    const float scale2 = scale1 * (float)NB2;      // exact pow2 multiple of scale1:
                                                   // floor(e*scale2) in [64*floor(e*scale1), +63]

    // ---- zero hist1 region ----
    for (int i = tid; i < SMW; i += NT) smem[i] = 0u;
    __syncthreads();

    const float4* __restrict__ src = (const float4*)(hsi + (size_t)g * HWSZ);
    unsigned short* __restrict__ h1  = (unsigned short*)smem;
    unsigned short* __restrict__ h1p = h1 + tid * H1S;   // private row

    // ---- Phase 1: HBM stream — total sum + coarse private count hist ----
    unsigned long long tot = 0ull;
    #pragma unroll 4
    for (int i = 0; i < HWSZ / 4 / NT; ++i) {      // 64 coalesced float4 iters
        float4 v = src[(size_t)i * NT + tid];
        #pragma unroll
        for (int j = 0; j < 4; ++j) {
            float h  = (&v.x)[j];
            float f1 = h * w;
            float e  = -f1 * __logf(f1);           // e in (0, emax]
            unsigned b1 = (unsigned)(e * scale1);
            b1 = min(b1, (unsigned)(NB1 - 1));
            tot += (unsigned long long)(unsigned)(e * FIXSCALE + 0.5f);
            h1p[b1] += 1;                          // private u16 RMW — no atomics
        }
    }
    totArr[tid] = tot;
    __syncthreads();

    // ---- reduce hist1 -> cnt1[128] ----
    {
        const int bin = tid & (NB1 - 1);
        const int seg = tid >> 7;                  // 0..1, 128 threads each
        unsigned s = 0u;
        for (int t = 0; t < 128; ++t) s += h1[(seg * 128 + t) * H1S + bin];
        part1[seg][bin] = s;
    }
    __syncthreads();
    if (tid < NB1) cnt1[tid] = part1[0][tid] + part1[1][tid];
    __syncthreads();

    // ---- locate level-1 boundary bin cb (scan from the top) ----
    if (tid == 0) {
        unsigned acc = 0u;
        int b = NB1 - 1;
        for (; b > 0; --b) {
            unsigned c = cnt1[b];
            if (acc + c >= KSEL) break;
            acc += c;
        }
        s_cb = b;
        s_accAbove = acc;                          // exact count strictly above bin cb
    }
    __syncthreads();
    const unsigned cb = (unsigned)s_cb;

    // ---- zero hist2 region (reuse union) ----
    for (int i = tid; i < SMW; i += NT) smem[i] = 0u;
    __syncthreads();

    unsigned* __restrict__ h2p = smem + tid * H2S; // private row

    // ---- Phase 2: L3-resident re-read — exact high sum + fine hist inside cb ----
    unsigned long long sumHigh = 0ull;
    #pragma unroll 2
    for (int i = 0; i < HWSZ / 4 / NT; ++i) {
        float4 v = src[(size_t)i * NT + tid];
        #pragma unroll
        for (int j = 0; j < 4; ++j) {
            float h  = (&v.x)[j];
            float f1 = h * w;
            float e  = -f1 * __logf(f1);           // bit-identical to phase 1
            unsigned b1 = (unsigned)(e * scale1);
            b1 = min(b1, (unsigned)(NB1 - 1));
            if (b1 > cb) {
                sumHigh += (unsigned long long)(unsigned)(e * FIXSCALE + 0.5f);
            } else if (b1 == cb) {
                unsigned s2 = (unsigned)(e * scale2) - cb * NB2;  // in [0,63] (pow2 scaling)
                s2 = min(s2, (unsigned)(NB2 - 1));
                // pack: cnt in bits[31:22] (max 256), q15 sum in bits[21:0]
                // (max 256 * 0.368 * 2^15 = 3.09e6 < 2^22 — no carry into cnt)
                h2p[s2] += (1u << 22) | (unsigned)(e * Q15SCALE + 0.5f);
            }
        }
    }
    highArr[tid] = sumHigh;
    __syncthreads();

    // ---- reduce hist2 -> cnt2/sum2 ----
    {
        const int bin = tid & (NB2 - 1);
        const int seg = tid >> 6;                  // 0..3, 64 threads each
        unsigned c = 0u, s = 0u;
        for (int t = 0; t < 64; ++t) {
            unsigned v = smem[(seg * 64 + t) * H2S + bin];
            c += v >> 22;
            s += v & 0x3FFFFFu;
        }
        pc2[seg][bin] = c;
        ps2[seg][bin] = s;
    }
    __syncthreads();
    if (tid < NB2) {
        cnt2[tid] = pc2[0][tid] + pc2[1][tid] + pc2[2][tid] + pc2[3][tid];
        sum2[tid] = ps2[0][tid] + ps2[1][tid] + ps2[2][tid] + ps2[3][tid];
    }
    // partial u64 reductions in parallel
    if (tid < 64) {
        totArr[tid]  = totArr[tid]  + totArr[tid + 64]  + totArr[tid + 128]  + totArr[tid + 192];
        highArr[tid] = highArr[tid] + highArr[tid + 64] + highArr[tid + 128] + highArr[tid + 192];
    }
    __syncthreads();

    if (tid == 0) {
        unsigned long long tt = 0ull, hh = 0ull;
        for (int i = 0; i < 64; ++i) { tt += totArr[i]; hh += highArr[i]; }
        total_sum[g] = (double)tt * (1.0 / (double)FIXSCALE);

        // level-2 scan from the top inside bin cb
        unsigned acc = s_accAbove;
        double sAcc = 0.0;
        int b = NB2 - 1;
        for (; b > 0; --b) {
            unsigned c = cnt2[b];
            if (acc + c >= KSEL) break;
            acc += c;
            sAcc += (double)sum2[b];
        }
        // boundary fine bin: (KSEL-acc) items at the bin's average value.
        // fine width = emax/8192 — same interpolation error budget as prior kernel.
        double take = (double)(KSEL - acc);
        double avg  = (cnt2[b] > 0u) ? ((double)sum2[b] / (double)cnt2[b]) : 0.0;
        topk_sum[g] = (double)hh * (1.0 / (double)FIXSCALE)
                    + (sAcc + take * avg) * (1.0 / (double)Q15SCALE);
    }
}

// ---------------- Final: channel deltas + stable top-3 indices ----------------
__global__ void final_kernel(const double* __restrict__ total_sum,
                             const double* __restrict__ topk_sum,
                             int* __restrict__ out) {
    __shared__ double delta[CCH];
    const int c = threadIdx.x;
    double th = 0.0, tot = 0.0;
    for (int b = 0; b < BN; ++b) {
        th  += topk_sum[b * CCH + c];
        tot += total_sum[b * CCH + c];
    }
    // ranking monotone in (mean_high - mean)
    delta[c] = th / ((double)BN * (double)KSEL) - tot / ((double)BN * (double)HWSZ);
    __syncthreads();
    if (c == 0) {
        int chosen[3];
        for (int j = 0; j < 3; ++j) {
            double bv = -1e300; int bi = 0;
            for (int i = 0; i < CCH; ++i) {
                bool skip = false;
                for (int jj = 0; jj < j; ++jj) if (chosen[jj] == i) skip = true;
                if (!skip && delta[i] > bv) { bv = delta[i]; bi = i; }  // strict >: lower idx wins ties
            }
            chosen[j] = bi;
            out[j] = bi;
        }
    }
}

extern "C" void kernel_launch(void* const* d_in, const int* in_sizes, int n_in,
                              void* d_out, int out_size, void* d_ws, size_t ws_size,
                              hipStream_t stream) {
    const float* hsi = (const float*)d_in[0];
    const float* w   = (const float*)d_in[1];
    int* out = (int*)d_out;

    char* ws = (char*)d_ws;
    double* total_sum = (double*)(ws);          // 512*8 = 4 KB
    double* topk_sum  = (double*)(ws + 4096);   // 4 KB

    hipLaunchKernelGGL(passA_kernel, dim3(NG), dim3(NT), 0, stream, hsi, w, total_sum, topk_sum);
    hipLaunchKernelGGL(final_kernel, dim3(1), dim3(CCH), 0, stream, total_sum, topk_sum, out);
}

// Round 2
// 241.250 us; speedup vs baseline: 1.1145x; 1.1145x over previous
//
#include <hip/hip_runtime.h>

#define HWSZ 65536      // H*W
#define KSEL 32768u     // int(0.5*H*W)
#define CCH  128        // channels
#define BN   4          // batch
#define NG   (CCH * BN) // 512 groups; group g = b*CCH + c, contiguous HWSZ floats
#define NT   512        // threads per block (8 waves) -> 2 blocks/CU, 16 waves/CU
#define NW   (NT / 64)  // 8 waves

#define NB1  32         // level-1 coarse bins
#define NB2  256        // level-2 sub-bins inside boundary bin (32*256 = 8192 total)
#define H1W  33         // u32 words per thread row: 32 bins * 4 byte-slots = 128 B + 4 B pad

#define FIXSCALE 1073741824.0f           // 2^30 fixed-point for e
#define SUMMASK  ((1ull << 47) - 1ull)   // q30 sum in bits[46:0], count in bits[63:47]

// Two streaming passes. Phase 1 (HBM): exact q30 total in registers + private
// per-thread 32-bin count histogram (4 independent byte-slots -> 4 LDS RMW
// chains in flight, no atomics). Phase 2 (L3-resident re-read): exact q30 sum
// of coarse bins > cb in registers; elements in boundary bin cb go through a
// packed (cnt<<47|q30) u64 LDS atomic into a 256-sub-bin histogram (~3-8% of
// elements -> negligible serialization). Fine grid = 8192 bins, same
// resolution + in-bin-average interpolation as the verified baseline.
__global__ void __launch_bounds__(NT) passA_kernel(
    const float* __restrict__ hsi, const float* __restrict__ wp,
    double* __restrict__ total_sum, double* __restrict__ topk_sum) {
    __shared__ unsigned h1[NT * H1W];              // 67584 B private byte hists
    __shared__ unsigned part1[16 * NB1];           // 2 KB partial bin sums
    __shared__ unsigned cnt1[NB1];                 // 128 B
    __shared__ unsigned long long hist2[NB2];      // 2 KB packed fine hist
    __shared__ unsigned sufc[NB2];                 // 1 KB suffix counts
    __shared__ unsigned long long sufs[NB2];       // 2 KB suffix q30 sums
    __shared__ unsigned long long wtot[NW];        // 64 B per-wave totals
    __shared__ unsigned long long whigh[NW];       // 64 B per-wave high sums
    __shared__ int s_cb;
    __shared__ unsigned s_acc;                     // exact count strictly above bin cb
    __shared__ int s_fb;

    const int g    = blockIdx.x;
    const int tid  = threadIdx.x;
    const int lane = tid & 63;
    const int wid  = tid >> 6;
    const float w  = wp[0];

    // upper bound on e = -f1*ln(f1), f1 in (0, w): 1/e if w>=1/e else -w ln w
    float emax = (w < 0.367879441f) ? (-w * __logf(w)) : 0.3678794412f;
    emax *= 1.000004f;                             // fp slack so no value exceeds range
    const float scale1 = (float)NB1 / emax;
    const float scale2 = scale1 * (float)NB2;      // exact pow2 multiple of scale1

    // ---- zero private hist region ----
    for (int i = tid; i < NT * H1W; i += NT) h1[i] = 0u;
    __syncthreads();

    const float4* __restrict__ src = (const float4*)(hsi + (size_t)g * HWSZ);
    unsigned char* __restrict__ h1b = ((unsigned char*)h1) + tid * (H1W * 4);

    // ---- Phase 1: HBM stream — exact total + coarse private count hist ----
    unsigned long long tot = 0ull;
    #pragma unroll 4
    for (int i = 0; i < HWSZ / 4 / NT; ++i) {      // 32 coalesced float4 iters
        float4 v = src[(size_t)i * NT + tid];
        #pragma unroll
        for (int j = 0; j < 4; ++j) {
            float h  = (&v.x)[j];
            float f1 = h * w;
            float e  = -f1 * __logf(f1);           // e in (0, emax]
            unsigned b1 = (unsigned)(e * scale1);
            b1 = min(b1, (unsigned)(NB1 - 1));
            tot += (unsigned long long)(unsigned)(e * FIXSCALE + 0.5f);
            h1b[(b1 << 2) | j] += 1;               // slot j: 4 independent RMW chains
        }
    }
    // per-wave u64 reduction (shuffle), leaders park in LDS
    #pragma unroll
    for (int off = 32; off > 0; off >>= 1) tot += __shfl_down(tot, off, 64);
    if (lane == 0) wtot[wid] = tot;
    __syncthreads();

    // ---- reduce h1 -> cnt1[32]: each u32 word holds 4 byte-slot counts of one bin ----
    {
        const int bin = tid & (NB1 - 1);
        const int ch  = tid >> 5;                  // 16 chunks of 32 rows
        unsigned s = 0u;
        #pragma unroll 4
        for (int r = 0; r < 32; ++r) {
            unsigned v = h1[(ch * 32 + r) * H1W + bin];
            unsigned t1 = (v & 0x00FF00FFu) + ((v >> 8) & 0x00FF00FFu);
            s += (t1 & 0xFFFFu) + (t1 >> 16);
        }
        part1[ch * NB1 + bin] = s;
    }
    __syncthreads();
    if (tid < NB1) {
        unsigned s = 0u;
        #pragma unroll
        for (int ch = 0; ch < 16; ++ch) s += part1[ch * NB1 + tid];
        cnt1[tid] = s;
    }
    __syncthreads();

    // ---- locate level-1 boundary bin cb (scan from the top; 32 bins, cheap) ----
    if (tid == 0) {
        unsigned acc = 0u;
        int b = NB1 - 1;
        for (; b > 0; --b) {
            unsigned c = cnt1[b];
            if (acc + c >= KSEL) break;
            acc += c;
        }
        s_cb = b;
        s_acc = acc;
    }
    if (tid < NB2) hist2[tid] = 0ull;
    __syncthreads();
    const unsigned cb = (unsigned)s_cb;

    // ---- Phase 2: L3-resident re-read — exact high sum + fine hist inside cb ----
    unsigned long long hs = 0ull;
    #pragma unroll 4
    for (int i = 0; i < HWSZ / 4 / NT; ++i) {
        float4 v = src[(size_t)i * NT + tid];
        #pragma unroll
        for (int j = 0; j < 4; ++j) {
            float h  = (&v.x)[j];
            float f1 = h * w;
            float e  = -f1 * __logf(f1);           // bit-identical to phase 1
            unsigned b1 = (unsigned)(e * scale1);
            b1 = min(b1, (unsigned)(NB1 - 1));
            unsigned q = (unsigned)(e * FIXSCALE + 0.5f);
            if (b1 > cb) {
                hs += q;
            } else if (b1 == cb) {
                int s2 = (int)(unsigned)(e * scale2) - (int)(cb << 8);
                s2 = max(0, min((int)(NB2 - 1), s2));   // both-side clamp (fp edge)
                atomicAdd(&hist2[s2], (1ull << 47) | (unsigned long long)q);
            }
        }
    }
    #pragma unroll
    for (int off = 32; off > 0; off >>= 1) hs += __shfl_down(hs, off, 64);
    if (lane == 0) whigh[wid] = hs;
    __syncthreads();

    // ---- parallel suffix scan over fine hist (counts + q30 sums) ----
    if (tid < NB2) {
        unsigned long long v = hist2[tid];
        sufc[tid] = (unsigned)(v >> 47);
        sufs[tid] = v & SUMMASK;
    }
    __syncthreads();
    #pragma unroll
    for (int off = 1; off < NB2; off <<= 1) {
        unsigned c = 0u; unsigned long long s = 0ull;
        if (tid < NB2) {
            c = sufc[tid]; s = sufs[tid];
            if (tid + off < NB2) { c += sufc[tid + off]; s += sufs[tid + off]; }
        }
        __syncthreads();
        if (tid < NB2) { sufc[tid] = c; sufs[tid] = s; }
        __syncthreads();
    }
    // sufc[i] = count of cb-elements in fine bins >= i (non-increasing)
    {
        const unsigned needed = KSEL - s_acc;      // >= 1 by construction of cb
        if (tid < NB2) {
            bool c0 = sufc[tid] >= needed;
            bool c1 = (tid == NB2 - 1) ? true : (sufc[tid + 1] < needed);
            if (c0 && c1) s_fb = tid;
        }
    }
    __syncthreads();

    if (tid == 0) {
        unsigned long long tt = 0ull, hh = 0ull;
        #pragma unroll
        for (int i = 0; i < NW; ++i) { tt += wtot[i]; hh += whigh[i]; }
        total_sum[g] = (double)tt * (1.0 / (double)FIXSCALE);

        const int fb = s_fb;
        const unsigned needed = KSEL - s_acc;
        unsigned cAbove = (fb < NB2 - 1) ? sufc[fb + 1] : 0u;
        unsigned long long sAbove = (fb < NB2 - 1) ? sufs[fb + 1] : 0ull;
        unsigned cf = sufc[fb] - cAbove;
        unsigned long long sf = sufs[fb] - sAbove;
        // boundary fine bin: (needed-cAbove) items at the bin's average value.
        // fine width = emax/8192 — same interpolation error budget as baseline.
        double take = (double)(needed - cAbove);
        double avg  = (cf > 0u) ? ((double)sf / (double)cf) : 0.0;
        topk_sum[g] = ((double)hh + (double)sAbove + take * avg)
                    * (1.0 / (double)FIXSCALE);
    }
}

// ---------------- Final: channel deltas + stable top-3 indices ----------------
__global__ void final_kernel(const double* __restrict__ total_sum,
                             const double* __restrict__ topk_sum,
                             int* __restrict__ out) {
    __shared__ double delta[CCH];
    const int c = threadIdx.x;
    double th = 0.0, tot = 0.0;
    for (int b = 0; b < BN; ++b) {
        th  += topk_sum[b * CCH + c];
        tot += total_sum[b * CCH + c];
    }
    // ranking monotone in (mean_high - mean)
    delta[c] = th / ((double)BN * (double)KSEL) - tot / ((double)BN * (double)HWSZ);
    __syncthreads();
    if (c == 0) {
        int chosen[3];
        for (int j = 0; j < 3; ++j) {
            double bv = -1e300; int bi = 0;
            for (int i = 0; i < CCH; ++i) {
                bool skip = false;
                for (int jj = 0; jj < j; ++jj) if (chosen[jj] == i) skip = true;
                if (!skip && delta[i] > bv) { bv = delta[i]; bi = i; }  // strict >: lower idx wins ties
            }
            chosen[j] = bi;
            out[j] = bi;
        }
    }
}

extern "C" void kernel_launch(void* const* d_in, const int* in_sizes, int n_in,
                              void* d_out, int out_size, void* d_ws, size_t ws_size,
                              hipStream_t stream) {
    const float* hsi = (const float*)d_in[0];
    const float* w   = (const float*)d_in[1];
    int* out = (int*)d_out;

    char* ws = (char*)d_ws;
    double* total_sum = (double*)(ws);          // 512*8 = 4 KB
    double* topk_sum  = (double*)(ws + 4096);   // 4 KB

    hipLaunchKernelGGL(passA_kernel, dim3(NG), dim3(NT), 0, stream, hsi, w, total_sum, topk_sum);
    hipLaunchKernelGGL(final_kernel, dim3(1), dim3(CCH), 0, stream, total_sum, topk_sum, out);
}

// Round 3
// 228.199 us; speedup vs baseline: 1.1783x; 1.0572x over previous
//
#include <hip/hip_runtime.h>

#define HWSZ 65536      // H*W
#define KSEL 32768u     // int(0.5*H*W)
#define CCH  128        // channels
#define BN   4          // batch
#define NG   (CCH * BN) // 512 groups; group g = b*CCH + c, contiguous HWSZ floats
#define NT   1024       // threads per block (16 waves) -> 2 blocks/CU = 32 waves/CU
#define NW   (NT / 64)  // 16 waves
#define ITER (HWSZ / 4 / NT)   // 16 float4 iterations per pass

#define NB1  12                // coarse bins: b1 = q>>25 in [0,11] (e < 0.375 always)
#define H1W  13                // u32 words per private row (12 bins*4 byte-slots + pad)
#define NB2  1024              // fine bins inside boundary coarse bin (12K effective)
#define QC   (-744261120.0f)   // -ln(2) * 2^30: q = (u32)(f1*log2(f1)*QC + 0.5)
#define SUMMASK ((1ull << 47) - 1ull)   // q30 sum bits[46:0], count bits[63:47]

// Two streaming passes, 100% occupancy. q = e*2^30 fixed point computed with one
// fma after v_log_f32; coarse/fine bins are pure shifts of q (no float scales).
// Pass 1 (HBM): exact q30 total (register u64) + private per-thread 12-bin count
// hist (byte slots, no atomics). Pass 2 (L3 re-read): exact q30 sum of coarse
// bins > cb in registers; boundary-bin elements go to a 1024-fine-bin packed
// (cnt<<47|q30) LDS atomic hist (~3-15% of elements). Fine width = 2^-15 in e —
// finer than the verified 8192-bin baseline; same in-bin-average interpolation.
__global__ void __launch_bounds__(NT, 8) passA_kernel(
    const float* __restrict__ hsi, const float* __restrict__ wp,
    double* __restrict__ total_sum, double* __restrict__ topk_sum) {
    __shared__ unsigned h1[NT * H1W];              // 53248 B private byte hists
    __shared__ unsigned long long hist2[NB2];      // 8192 B packed fine hist
    __shared__ unsigned part1[64 * NB1];           // 3072 B partial bin sums
    __shared__ unsigned cnt1[NB1];                 // 48 B
    __shared__ unsigned long long wtot[NW];        // 128 B
    __shared__ unsigned long long whigh[NW];       // 128 B
    __shared__ int s_cb;
    __shared__ unsigned s_acc;                     // exact count strictly above bin cb
    __shared__ int s_fb;
    // total ~64.8 KB -> 2 blocks/CU

    const int g    = blockIdx.x;
    const int tid  = threadIdx.x;
    const int lane = tid & 63;
    const int wid  = tid >> 6;
    const float w  = wp[0];

    for (int i = tid; i < NT * H1W; i += NT) h1[i] = 0u;
    __syncthreads();

    const float4* __restrict__ src = (const float4*)(hsi + (size_t)g * HWSZ);
    unsigned char* __restrict__ h1b = (unsigned char*)h1;
    const unsigned lbase = (unsigned)tid * (H1W * 4);

    // ---- Phase 1: HBM stream — exact q30 total + coarse private count hist ----
    unsigned long long tot = 0ull;
    #pragma unroll 2
    for (int i = 0; i < ITER; ++i) {
        float4 v = src[i * NT + tid];
        unsigned qs = 0u;                          // 4*q < 2^31: safe u32 batch
        #pragma unroll
        for (int j = 0; j < 4; ++j) {
            float f1 = (&v.x)[j] * w;
            float m  = f1 * __log2f(f1);           // v_log_f32 + v_mul
            unsigned q = (unsigned)fmaf(m, QC, 0.5f);   // e*2^30, q < 2^29
            qs += q;
            unsigned b1 = q >> 25;                 // coarse bin, <= 11 always
            h1b[lbase + (b1 << 2) + j] += 1;       // byte slot j: private RMW
        }
        tot += qs;
    }
    #pragma unroll
    for (int off = 32; off > 0; off >>= 1) tot += __shfl_down(tot, off, 64);
    if (lane == 0) wtot[wid] = tot;
    __syncthreads();

    // ---- reduce h1 -> cnt1[12] (SWAR byte sums) ----
    {
        int bin = tid & 15;
        int ch  = tid >> 4;                        // 64 chunks of 16 rows
        if (bin < NB1) {
            unsigned s = 0u;
            #pragma unroll 4
            for (int r = 0; r < 16; ++r) {
                unsigned vv = h1[(ch * 16 + r) * H1W + bin];
                unsigned t1 = (vv & 0x00FF00FFu) + ((vv >> 8) & 0x00FF00FFu);
                s += (t1 & 0xFFFFu) + (t1 >> 16);
            }
            part1[ch * NB1 + bin] = s;
        }
    }
    __syncthreads();
    if (tid < NB1) {
        unsigned s = 0u;
        #pragma unroll
        for (int ch = 0; ch < 64; ++ch) s += part1[ch * NB1 + tid];
        cnt1[tid] = s;
    }
    __syncthreads();
    if (tid == 0) {
        unsigned acc = 0u;
        int b = NB1 - 1;
        for (; b > 0; --b) {
            unsigned c = cnt1[b];
            if (acc + c >= KSEL) break;
            acc += c;
        }
        s_cb = b;
        s_acc = acc;
    }
    hist2[tid] = 0ull;                             // NT == NB2
    __syncthreads();
    const unsigned cb = (unsigned)s_cb;

    // ---- Phase 2: L3-resident re-read — exact high sum + fine hist inside cb ----
    unsigned long long hsum = 0ull;
    #pragma unroll 2
    for (int i = 0; i < ITER; ++i) {
        float4 v = src[i * NT + tid];
        unsigned qs = 0u;
        #pragma unroll
        for (int j = 0; j < 4; ++j) {
            float f1 = (&v.x)[j] * w;
            float m  = f1 * __log2f(f1);
            unsigned q = (unsigned)fmaf(m, QC, 0.5f);   // bit-identical to phase 1
            unsigned b1 = q >> 25;
            qs += (b1 > cb) ? q : 0u;
            if (b1 == cb) {
                unsigned fbin = (q >> 15) & (NB2 - 1);  // exact: 2^25/2^15 = 1024
                atomicAdd(&hist2[fbin], (1ull << 47) | (unsigned long long)q);
            }
        }
        hsum += qs;
    }
    #pragma unroll
    for (int off = 32; off > 0; off >>= 1) hsum += __shfl_down(hsum, off, 64);
    if (lane == 0) whigh[wid] = hsum;
    __syncthreads();

    // ---- in-place parallel suffix scan on packed hist2 (cnt 17b ok, sum < 2^45) ----
    for (int off = 1; off < NB2; off <<= 1) {
        unsigned long long a = hist2[tid];
        unsigned long long b = (tid + off < NB2) ? hist2[tid + off] : 0ull;
        __syncthreads();
        hist2[tid] = a + b;
        __syncthreads();
    }
    const unsigned needed = KSEL - s_acc;          // >= 1 by construction of cb
    {
        unsigned c0 = (unsigned)(hist2[tid] >> 47);
        unsigned c1 = (tid == NB2 - 1) ? 0u : (unsigned)(hist2[tid + 1] >> 47);
        if (c0 >= needed && c1 < needed) s_fb = tid;
    }
    __syncthreads();

    if (tid == 0) {
        unsigned long long tt = 0ull, hh = 0ull;
        #pragma unroll
        for (int i = 0; i < NW; ++i) { tt += wtot[i]; hh += whigh[i]; }
        total_sum[g] = (double)tt * (1.0 / 1073741824.0);

        const int fb = s_fb;
        unsigned long long above = (fb < NB2 - 1) ? hist2[fb + 1] : 0ull;
        unsigned cA = (unsigned)(above >> 47);
        unsigned long long sA = above & SUMMASK;
        unsigned long long cur = hist2[fb];
        unsigned cf = (unsigned)(cur >> 47) - cA;
        unsigned long long sf = (cur & SUMMASK) - sA;
        // boundary fine bin: (needed-cA) items at the bin's average value.
        double take = (double)(needed - cA);
        double avg  = (cf > 0u) ? ((double)sf / (double)cf) : 0.0;
        topk_sum[g] = ((double)hh + (double)sA + take * avg) * (1.0 / 1073741824.0);
    }
}

// ---------------- Final: channel deltas + stable top-3 indices ----------------
__global__ void final_kernel(const double* __restrict__ total_sum,
                             const double* __restrict__ topk_sum,
                             int* __restrict__ out) {
    __shared__ double delta[CCH];
    const int c = threadIdx.x;
    double th = 0.0, tot = 0.0;
    for (int b = 0; b < BN; ++b) {
        th  += topk_sum[b * CCH + c];
        tot += total_sum[b * CCH + c];
    }
    // ranking monotone in (mean_high - mean)
    delta[c] = th / ((double)BN * (double)KSEL) - tot / ((double)BN * (double)HWSZ);
    __syncthreads();
    if (c == 0) {
        int chosen[3];
        for (int j = 0; j < 3; ++j) {
            double bv = -1e300; int bi = 0;
            for (int i = 0; i < CCH; ++i) {
                bool skip = false;
                for (int jj = 0; jj < j; ++jj) if (chosen[jj] == i) skip = true;
                if (!skip && delta[i] > bv) { bv = delta[i]; bi = i; }  // strict >: lower idx wins ties
            }
            chosen[j] = bi;
            out[j] = bi;
        }
    }
}

extern "C" void kernel_launch(void* const* d_in, const int* in_sizes, int n_in,
                              void* d_out, int out_size, void* d_ws, size_t ws_size,
                              hipStream_t stream) {
    const float* hsi = (const float*)d_in[0];
    const float* w   = (const float*)d_in[1];
    int* out = (int*)d_out;

    char* ws = (char*)d_ws;
    double* total_sum = (double*)(ws);          // 512*8 = 4 KB
    double* topk_sum  = (double*)(ws + 4096);   // 4 KB

    hipLaunchKernelGGL(passA_kernel, dim3(NG), dim3(NT), 0, stream, hsi, w, total_sum, topk_sum);
    hipLaunchKernelGGL(final_kernel, dim3(1), dim3(CCH), 0, stream, total_sum, topk_sum, out);
}